// Round 10
// baseline (521.090 us; speedup 1.0000x reference)
//
#include <hip/hip_runtime.h>
#include <hip/hip_cooperative_groups.h>
#include <math.h>

namespace cg = cooperative_groups;

#define R_NODES 1152
#define DIGITS 10
#define OUT_CH 16
#define IN_CH 8
#define BATCH 256
#define COLS 160            // DIGITS*OUT_CH
#define W_PER_R 1280        // DIGITS*OUT_CH*IN_CH
#define NSPLIT 192          // K-split: 6 r-rows per S-unit
#define RPS 6               // rows per split
#define SGRP 102            // W-LDS colgroup stride (conflict-free for g=0..15)
#define SROW (16 * SGRP)    // 1632 floats per W row
#define UPAD 52             // u-LDS batch stride
#define YBLK 8              // A-phase batch blocks (32 b each)
#define AB_STRIDE (YBLK * R_NODES * DIGITS)   // 92160 floats per ab iteration-buffer
#define S_UNITS (NSPLIT * 4)      // 768: (split, 64-batch block)
#define R_UNITS (BATCH * COLS / 64)   // 640
#define A_UNITS (R_NODES / 8 * YBLK)  // 1152
#define V_UNITS (BATCH * COLS / 256)  // 160
#define LDS_FLOATS (RPS * SROW + 64 * UPAD)   // 9792 + 3328 = 13120 (52.48 KB)

// One persistent cooperative kernel: 3 routing iterations, phases separated by
// grid.sync(). r9 post-mortem: 11 serialized small dispatches paid ~130us of
// launch/drain overhead on ~35us of compute; intra-kernel tuning was a no-op.
__global__ __launch_bounds__(256, 3) void k_fused(
    const float* __restrict__ u,      // [B][R][8]
    const float* __restrict__ W,      // [R][10][16][8]
    float* __restrict__ part,         // [NSPLIT][B][160]
    float* __restrict__ s,            // [B][160]
    float* __restrict__ sqpart,       // [R_UNITS] deterministic sum-sq partials
    float* __restrict__ ab,           // [2][YBLK][R][10] agreement partials
    float* __restrict__ out)          // [B][160]
{
    cg::grid_group grid = cg::this_grid();
    __shared__ float lds[LDS_FLOATS];
    __shared__ float cs[64];
    __shared__ float qsh;

    const int t = threadIdx.x;
    const int nb = gridDim.x;
    float* const wt = lds;                   // S: 6 x 1632
    float* const ut = lds + RPS * SROW;      // S: 64 x 52

    for (int it = 0; it < 3; ++it) {
        // ================= S-phase: part[split][b][col] =================
        for (int unit = blockIdx.x; unit < S_UNITS; unit += nb) {
            const int split = unit >> 2;
            const int b0 = (unit & 3) * 64;
            const int g = t & 15;
            const int bs = t >> 4;
            const int r0 = split * RPS;
            __syncthreads();   // previous phase/unit LDS readers done

            // 1. u-tile loads (3 float4/thread, coalesced)
            float4 ur[3]; int ub_[3], uq_[3];
#pragma unroll
            for (int p = 0; p < 3; ++p) {
                int idx = t + p * 256;
                int b = idx / 12, q = idx - b * 12;
                ub_[p] = b; uq_[p] = q;
                ur[p] = ((const float4*)(u + (size_t)(b0 + b) * (R_NODES * IN_CH)
                                           + (size_t)r0 * IN_CH))[q];
            }
            // 2. W loads (8 float4/thread, guarded: 1920 total)
            float4 wr[8];
            {
                const float4* Wg = (const float4*)(W + (size_t)r0 * W_PER_R);
#pragma unroll
                for (int p = 0; p < 8; ++p) {
                    int idx = t + p * 256;
                    wr[p] = (idx < RPS * W_PER_R / 4) ? Wg[idx]
                                                      : make_float4(0.f, 0.f, 0.f, 0.f);
                }
            }
            // 3. write u-tile (drains only u loads; W stays in flight)
#pragma unroll
            for (int p = 0; p < 3; ++p)
                *(float4*)&ut[ub_[p] * UPAD + uq_[p] * 4] = ur[p];

            // 4. c logits (0 if it==0 -> softmax = 0.1)
            if (t < RPS * DIGITS) {
                float a = 0.f;
                int r_l = t / 10, d = t - r_l * 10;
                const float* p0 = ab + (size_t)(r0 + r_l) * DIGITS + d;
                for (int bu = 0; bu < it; ++bu)
#pragma unroll
                    for (int yy = 0; yy < YBLK; ++yy)
                        a += p0[(size_t)bu * AB_STRIDE + (size_t)yy * (R_NODES * DIGITS)];
                cs[t] = a;
            }
            __syncthreads();
            if (t < RPS) {
                float e[DIGITS];
                float m = -1e30f;
#pragma unroll
                for (int d = 0; d < DIGITS; ++d) m = fmaxf(m, cs[t*10 + d]);
                float ssum = 0.f;
#pragma unroll
                for (int d = 0; d < DIGITS; ++d) { e[d] = expf(cs[t*10 + d] - m); ssum += e[d]; }
                float inv = 1.f / ssum;
#pragma unroll
                for (int d = 0; d < DIGITS; ++d) cs[t*10 + d] = e[d] * inv;
            }
            __syncthreads();

            // 5. scale W by c, write swizzled LDS
#pragma unroll
            for (int p = 0; p < 8; ++p) {
                int e4 = t + p * 256;
                if (e4 < RPS * W_PER_R / 4) {
                    int e  = e4 * 4;
                    int r_l = e4 / 320;
                    int rem = e - r_l * W_PER_R;
                    int col = rem >> 3, i0 = e & 7;
                    int cg_ = col / 10, cj = col - cg_ * 10;
                    float cv = cs[r_l * 10 + (col >> 4)];
                    float2* dst = (float2*)&wt[r_l * SROW + cg_ * SGRP + cj * 10 + i0];
                    dst[0] = make_float2(wr[p].x * cv, wr[p].y * cv);
                    dst[1] = make_float2(wr[p].z * cv, wr[p].w * cv);
                }
            }
            __syncthreads();

            // 6. compute: pure LDS + FMA
            float acc[4][10];
#pragma unroll
            for (int jj = 0; jj < 4; ++jj)
#pragma unroll
                for (int j = 0; j < 10; ++j) acc[jj][j] = 0.f;

#pragma unroll 2
            for (int r_l = 0; r_l < RPS; ++r_l) {
                float uu[4][8];
#pragma unroll
                for (int jj = 0; jj < 4; ++jj) {
                    const float* up = &ut[(bs + jj * 16) * UPAD + r_l * 8];
                    float4 a0 = *(const float4*)up;
                    float4 a1 = *(const float4*)(up + 4);
                    uu[jj][0]=a0.x; uu[jj][1]=a0.y; uu[jj][2]=a0.z; uu[jj][3]=a0.w;
                    uu[jj][4]=a1.x; uu[jj][5]=a1.y; uu[jj][6]=a1.z; uu[jj][7]=a1.w;
                }
                const float* wrow = &wt[r_l * SROW + g * SGRP];
#pragma unroll
                for (int j = 0; j < 10; ++j) {
                    const float2* wp = (const float2*)(wrow + j * 10);
                    float2 w01 = wp[0], w23 = wp[1], w45 = wp[2], w67 = wp[3];
#pragma unroll
                    for (int jj = 0; jj < 4; ++jj) {
                        float a = acc[jj][j];
                        a = fmaf(w01.x, uu[jj][0], a);
                        a = fmaf(w01.y, uu[jj][1], a);
                        a = fmaf(w23.x, uu[jj][2], a);
                        a = fmaf(w23.y, uu[jj][3], a);
                        a = fmaf(w45.x, uu[jj][4], a);
                        a = fmaf(w45.y, uu[jj][5], a);
                        a = fmaf(w67.x, uu[jj][6], a);
                        a = fmaf(w67.y, uu[jj][7], a);
                        acc[jj][j] = a;
                    }
                }
            }
            float* pp = part + (size_t)split * (BATCH * COLS) + (size_t)b0 * COLS;
#pragma unroll
            for (int jj = 0; jj < 4; ++jj) {
                float* row = pp + (size_t)(bs + jj * 16) * COLS + g * 10;
#pragma unroll
                for (int j = 0; j < 10; ++j) row[j] = acc[jj][j];
            }
        }
        grid.sync();

        // ================= R-phase: s = reduce(part); sqpart =================
        for (int unit = blockIdx.x; unit < R_UNITS; unit += nb) {
            const int e0 = unit * 64;
            const int el = t & 63, q = t >> 6;
            __syncthreads();
            float v = 0.f;
            for (int sp = q; sp < NSPLIT; sp += 4)
                v += part[(size_t)sp * (BATCH * COLS) + e0 + el];
            lds[t] = v;
            __syncthreads();
            if (t < 64) {
                float vv = lds[t] + lds[t + 64] + lds[t + 128] + lds[t + 192];
                s[e0 + t] = vv;
                float x = vv * vv;
#pragma unroll
                for (int off = 32; off > 0; off >>= 1)
                    x += __shfl_down(x, off, 64);
                if (t == 0) sqpart[unit] = x;
            }
        }
        grid.sync();

        // ---- every block: total sq -> scale (deterministic fixed-order sum)
        if (t < 64) {
            float qv = 0.f;
#pragma unroll
            for (int p = 0; p < R_UNITS / 64; ++p) qv += sqpart[t + p * 64];
#pragma unroll
            for (int off = 32; off > 0; off >>= 1)
                qv += __shfl_down(qv, off, 64);
            if (t == 0) qsh = qv;
        }
        __syncthreads();
        const float qtot = qsh;
        const float scale = sqrtf(qtot) / (1.f + qtot);

        if (it < 2) {
            // ================= A-phase: ab[it][y][r][d] =================
            for (int unit = blockIdx.x; unit < A_UNITS; unit += nb) {
                const int rblk = unit >> 3;
                const int bstart = (unit & 7) * 32;
                const int r = rblk * 8 + (t >> 5);
                const int tt = t & 31;
                float* const st = lds;            // 32 x 160
                float* const u2 = lds + 32 * COLS; // 32 x 64
                __syncthreads();
                {
                    const float4* sp = (const float4*)(s + (size_t)bstart * COLS);
#pragma unroll
                    for (int p = 0; p < 5; ++p) ((float4*)st)[t + p * 256] = sp[t + p * 256];
                }
#pragma unroll
                for (int p = 0; p < 2; ++p) {
                    int idx = t + p * 256;
                    int bb = idx >> 4, qq = idx & 15;
                    ((float4*)u2)[idx] =
                        ((const float4*)(u + (size_t)(bstart + bb) * (R_NODES*IN_CH)
                                           + (size_t)rblk * 64))[qq];
                }
                float wreg[5][8];
#pragma unroll
                for (int k = 0; k < 5; ++k) {
                    const float4* wp = (const float4*)(W + (size_t)r * W_PER_R
                                                         + (size_t)(tt + 32*k) * IN_CH);
                    float4 w0 = wp[0], w1 = wp[1];
                    wreg[k][0]=w0.x; wreg[k][1]=w0.y; wreg[k][2]=w0.z; wreg[k][3]=w0.w;
                    wreg[k][4]=w1.x; wreg[k][5]=w1.y; wreg[k][6]=w1.z; wreg[k][7]=w1.w;
                }
                __syncthreads();

                float acc[5] = {0.f, 0.f, 0.f, 0.f, 0.f};
#pragma unroll 2
                for (int b = 0; b < 32; ++b) {
                    const float* ub = &u2[b * 64 + (t >> 5) * 8];
                    float4 a0 = *(const float4*)ub;
                    float4 a1 = *(const float4*)(ub + 4);
                    const float* sb = &st[b * COLS];
#pragma unroll
                    for (int k = 0; k < 5; ++k) {
                        float vv = sb[tt + 32*k];
                        float uh;
                        uh = wreg[k][0] * a0.x;
                        uh = fmaf(wreg[k][1], a0.y, uh);
                        uh = fmaf(wreg[k][2], a0.z, uh);
                        uh = fmaf(wreg[k][3], a0.w, uh);
                        uh = fmaf(wreg[k][4], a1.x, uh);
                        uh = fmaf(wreg[k][5], a1.y, uh);
                        uh = fmaf(wreg[k][6], a1.z, uh);
                        uh = fmaf(wreg[k][7], a1.w, uh);
                        acc[k] = fmaf(uh, vv, acc[k]);
                    }
                }
                float* abp = ab + (size_t)it * AB_STRIDE
                               + (size_t)(unit & 7) * (R_NODES * DIGITS) + r * DIGITS;
#pragma unroll
                for (int k = 0; k < 5; ++k) {
                    float x = acc[k] * scale;
                    x += __shfl_xor(x, 1, 64);
                    x += __shfl_xor(x, 2, 64);
                    x += __shfl_xor(x, 4, 64);
                    x += __shfl_xor(x, 8, 64);
                    if ((tt & 15) == 0) abp[(tt >> 4) + 2*k] = x;
                }
            }
            grid.sync();   // ab ready for next iteration's softmax
        } else {
            // ================= V-phase: out = s * scale =================
            for (int unit = blockIdx.x; unit < V_UNITS; unit += nb) {
                int e = unit * 256 + t;
                out[e] = s[e] * scale;
            }
        }
    }
}

extern "C" void kernel_launch(void* const* d_in, const int* in_sizes, int n_in,
                              void* d_out, int out_size, void* d_ws, size_t ws_size,
                              hipStream_t stream)
{
    const float* u = (const float*)d_in[0];   // (256, 1152, 8)
    const float* W = (const float*)d_in[1];   // (1, 1152, 10, 16, 8)
    float* out = (float*)d_out;               // (256, 10, 16)
    float* ws = (float*)d_ws;

    float* s      = ws;                        // 40960 floats
    float* sqpart = ws + 40960;                // 640 (+pad 64)
    float* ab     = ws + 41664;                // 2 * 92160
    float* part   = ws + 41664 + 2 * AB_STRIDE;  // 192 * 40960 (~31.5 MB)

    int maxb = 0;
    hipOccupancyMaxActiveBlocksPerMultiprocessor(&maxb, k_fused, 256, 0);
    int grid = maxb * 256;                     // 256 CUs on MI355X
    if (grid > S_UNITS) grid = S_UNITS;
    if (grid < 1) grid = 1;

    void* args[] = {(void*)&u, (void*)&W, (void*)&part, (void*)&s,
                    (void*)&sqpart, (void*)&ab, (void*)&out};
    hipLaunchCooperativeKernel((void*)k_fused, dim3(grid), dim3(256),
                               args, 0, stream);
}